// Round 1
// baseline (934.856 us; speedup 1.0000x reference)
//
#include <hip/hip_runtime.h>
#include <hip/hip_bf16.h>

// RGCN (2 relations, d=128, two layers) for MI355X.
// Strategy: aggregate-then-transform.
//   agg[n, r, :] = mean over in-edges (rel r) of x[src]
//   out[n]       = agg[n,0]@W_r0 + agg[n,1]@W_r1 + x_in[n]@root + bias
// realized as one fused GEMM  [N x 384] @ [384 x 128].
// CSR by (dst*2 + etype) built on device each call (graph-capture safe).

#define NSEG_BLOCK 1024   // elements per scan block

// ---------------- CSR build ----------------

__global__ __launch_bounds__(256) void count_edges(
    const int* __restrict__ ea, const int* __restrict__ eb,
    int E, int* __restrict__ cnt) {
  int total = 2 * E;
  for (int i = blockIdx.x * blockDim.x + threadIdx.x; i < total;
       i += gridDim.x * blockDim.x) {
    int seg;
    if (i < E) seg = ea[E + i] * 2;            // relation 0, dst row
    else       seg = eb[E + (i - E)] * 2 + 1;  // relation 1
    atomicAdd(&cnt[seg], 1);
  }
}

__global__ __launch_bounds__(256) void scan_block_sums(
    const int* __restrict__ cnt, int* __restrict__ bsums, int nseg) {
  __shared__ int sdata[256];
  int base = blockIdx.x * NSEG_BLOCK;
  int s = 0;
#pragma unroll
  for (int j = 0; j < 4; ++j) {
    int i = base + threadIdx.x * 4 + j;
    if (i < nseg) s += cnt[i];
  }
  sdata[threadIdx.x] = s;
  __syncthreads();
  for (int off = 128; off > 0; off >>= 1) {
    if (threadIdx.x < off) sdata[threadIdx.x] += sdata[threadIdx.x + off];
    __syncthreads();
  }
  if (threadIdx.x == 0) bsums[blockIdx.x] = sdata[0];
}

__global__ __launch_bounds__(256) void scan_bsums(
    const int* __restrict__ bsums, int* __restrict__ boffs, int nblk) {
  __shared__ int sdata[256];
  int v = (threadIdx.x < nblk) ? bsums[threadIdx.x] : 0;
  sdata[threadIdx.x] = v;
  __syncthreads();
  for (int off = 1; off < 256; off <<= 1) {
    int t = (threadIdx.x >= (unsigned)off) ? sdata[threadIdx.x - off] : 0;
    __syncthreads();
    sdata[threadIdx.x] += t;
    __syncthreads();
  }
  if (threadIdx.x < nblk) boffs[threadIdx.x] = sdata[threadIdx.x] - v;  // exclusive
}

__global__ __launch_bounds__(256) void scan_final(
    const int* __restrict__ cnt, const int* __restrict__ boffs,
    int* __restrict__ offs, int* __restrict__ cursor,
    float* __restrict__ invc, int nseg) {
  __shared__ int sdata[256];
  int base = blockIdx.x * NSEG_BLOCK;
  int loc[4];
  int c4[4];
  int s = 0;
#pragma unroll
  for (int j = 0; j < 4; ++j) {
    int i = base + threadIdx.x * 4 + j;
    int c = (i < nseg) ? cnt[i] : 0;
    c4[j] = c;
    loc[j] = s;
    s += c;
  }
  sdata[threadIdx.x] = s;
  __syncthreads();
  int inc = s;
  for (int off = 1; off < 256; off <<= 1) {
    int t = (threadIdx.x >= (unsigned)off) ? sdata[threadIdx.x - off] : 0;
    __syncthreads();
    sdata[threadIdx.x] += t;
    __syncthreads();
  }
  int excl = sdata[threadIdx.x] - inc + boffs[blockIdx.x];
#pragma unroll
  for (int j = 0; j < 4; ++j) {
    int i = base + threadIdx.x * 4 + j;
    if (i < nseg) {
      int o = excl + loc[j];
      offs[i] = o;
      cursor[i] = o;
      invc[i] = 1.0f / (float)max(c4[j], 1);
    }
  }
}

__global__ __launch_bounds__(256) void fill_edges(
    const int* __restrict__ ea, const int* __restrict__ eb,
    int E, int* __restrict__ cursor, int* __restrict__ csr) {
  int total = 2 * E;
  for (int i = blockIdx.x * blockDim.x + threadIdx.x; i < total;
       i += gridDim.x * blockDim.x) {
    int src, seg;
    if (i < E) { src = ea[i];     seg = ea[E + i] * 2; }
    else       { src = eb[i - E]; seg = eb[E + (i - E)] * 2 + 1; }
    int pos = atomicAdd(&cursor[seg], 1);
    csr[pos] = src;
  }
}

// ---------------- aggregation (gather, one wave per segment) ----------------

__global__ __launch_bounds__(256) void agg_kernel(
    const float* __restrict__ xin,   // [N][128]
    const int* __restrict__ csr, const int* __restrict__ offs,
    const int* __restrict__ cnt, const float* __restrict__ invc,
    float* __restrict__ agg,         // [nseg][128]  (== [N][256])
    int nseg) {
  int wid = (blockIdx.x * blockDim.x + threadIdx.x) >> 6;  // wave id = segment
  int lane = threadIdx.x & 63;
  if (wid >= nseg) return;
  int beg = offs[wid];
  int end = beg + cnt[wid];
  float ax = 0.f, ay = 0.f;
  for (int e = beg; e < end; ++e) {
    int s = csr[e];
    const float2 v = *(const float2*)(xin + (size_t)s * 128 + lane * 2);
    ax += v.x;
    ay += v.y;
  }
  float inv = invc[wid];
  float2 r;
  r.x = ax * inv;
  r.y = ay * inv;
  *(float2*)(agg + (size_t)wid * 128 + lane * 2) = r;
}

// ---------------- fused GEMM: out = [agg | xin] @ [W | root] + bias ----------

#define BM 64
#define BK 64
#define BN 128

template <bool RELU>
__global__ __launch_bounds__(256) void fused_gemm(
    const float* __restrict__ agg,   // [N][256]
    const float* __restrict__ xin,   // [N][128]
    const float* __restrict__ W,     // [256][128] (W[r][i][o], r stacked)
    const float* __restrict__ root,  // [128][128]
    const float* __restrict__ bias,  // [128]
    float* __restrict__ out,         // [N][128]
    int N) {
  __shared__ float As[BK][BM + 4];  // transposed: As[k][m]
  __shared__ float Bs[BK][BN];
  int tid = threadIdx.x;
  int colt = tid & 15;   // 0..15 -> 8 cols each
  int rowt = tid >> 4;   // 0..15 -> 4 rows each
  int mbase = blockIdx.x * BM;

  float acc[4][8];
#pragma unroll
  for (int i = 0; i < 4; ++i)
#pragma unroll
    for (int j = 0; j < 8; ++j) acc[i][j] = 0.f;

  for (int kbase = 0; kbase < 384; kbase += BK) {
    // A tile: 64 rows x 64 k  (1024 float4, 4 per thread)
#pragma unroll
    for (int j = 0; j < 4; ++j) {
      int idx = tid + j * 256;  // 0..1023
      int m = idx >> 4;
      int kq = idx & 15;
      int k = kbase + kq * 4;
      int n = mbase + m;
      float4 v = make_float4(0.f, 0.f, 0.f, 0.f);
      if (n < N) {
        if (k < 256) v = *(const float4*)(agg + (size_t)n * 256 + k);
        else         v = *(const float4*)(xin + (size_t)n * 128 + (k - 256));
      }
      As[kq * 4 + 0][m] = v.x;
      As[kq * 4 + 1][m] = v.y;
      As[kq * 4 + 2][m] = v.z;
      As[kq * 4 + 3][m] = v.w;
    }
    // B tile: 64 k x 128 cols (2048 float4, 8 per thread)
#pragma unroll
    for (int j = 0; j < 8; ++j) {
      int idx = tid + j * 256;  // 0..2047
      int kr = idx >> 5;
      int cq = idx & 31;
      int k = kbase + kr;
      const float* src = (k < 256) ? (W + (size_t)k * 128 + cq * 4)
                                   : (root + (size_t)(k - 256) * 128 + cq * 4);
      *(float4*)(&Bs[kr][cq * 4]) = *(const float4*)src;
    }
    __syncthreads();
#pragma unroll 16
    for (int kk = 0; kk < BK; ++kk) {
      float4 a = *(const float4*)(&As[kk][rowt * 4]);
      float4 b0 = *(const float4*)(&Bs[kk][colt * 8]);
      float4 b1 = *(const float4*)(&Bs[kk][colt * 8 + 4]);
      float av[4] = {a.x, a.y, a.z, a.w};
      float bv[8] = {b0.x, b0.y, b0.z, b0.w, b1.x, b1.y, b1.z, b1.w};
#pragma unroll
      for (int i = 0; i < 4; ++i)
#pragma unroll
        for (int jj = 0; jj < 8; ++jj) acc[i][jj] += av[i] * bv[jj];
    }
    __syncthreads();
  }

#pragma unroll
  for (int i = 0; i < 4; ++i) {
    int n = mbase + rowt * 4 + i;
    if (n >= N) continue;
    float4 o0, o1;
    int o = colt * 8;
    o0.x = acc[i][0] + bias[o + 0];
    o0.y = acc[i][1] + bias[o + 1];
    o0.z = acc[i][2] + bias[o + 2];
    o0.w = acc[i][3] + bias[o + 3];
    o1.x = acc[i][4] + bias[o + 4];
    o1.y = acc[i][5] + bias[o + 5];
    o1.z = acc[i][6] + bias[o + 6];
    o1.w = acc[i][7] + bias[o + 7];
    if (RELU) {
      o0.x = fmaxf(o0.x, 0.f); o0.y = fmaxf(o0.y, 0.f);
      o0.z = fmaxf(o0.z, 0.f); o0.w = fmaxf(o0.w, 0.f);
      o1.x = fmaxf(o1.x, 0.f); o1.y = fmaxf(o1.y, 0.f);
      o1.z = fmaxf(o1.z, 0.f); o1.w = fmaxf(o1.w, 0.f);
    }
    *(float4*)(out + (size_t)n * 128 + o) = o0;
    *(float4*)(out + (size_t)n * 128 + o + 4) = o1;
  }
}

// ---------------- launch ----------------

extern "C" void kernel_launch(void* const* d_in, const int* in_sizes, int n_in,
                              void* d_out, int out_size, void* d_ws, size_t ws_size,
                              hipStream_t stream) {
  const float* x     = (const float*)d_in[0];
  const int*   ea    = (const int*)d_in[1];
  const int*   eb    = (const int*)d_in[2];
  const float* W1    = (const float*)d_in[3];
  const float* root1 = (const float*)d_in[4];
  const float* b1    = (const float*)d_in[5];
  const float* W2    = (const float*)d_in[6];
  const float* root2 = (const float*)d_in[7];
  const float* b2    = (const float*)d_in[8];
  float* out = (float*)d_out;

  const int N = in_sizes[0] / 128;
  const int E = in_sizes[1] / 2;
  const int nseg = N * 2;
  const int nblk = (nseg + NSEG_BLOCK - 1) / NSEG_BLOCK;  // 196 for N=100000

  // workspace carve-up
  char* p = (char*)d_ws;
  float* agg = (float*)p;      p += (size_t)N * 256 * sizeof(float);
  float* hbuf = (float*)p;     p += (size_t)N * 128 * sizeof(float);
  int* cnt = (int*)p;          p += (size_t)nseg * sizeof(int);
  int* offs = (int*)p;         p += (size_t)nseg * sizeof(int);
  int* cursor = (int*)p;       p += (size_t)nseg * sizeof(int);
  float* invc = (float*)p;     p += (size_t)nseg * sizeof(float);
  int* bsums = (int*)p;        p += 1024 * sizeof(int);
  int* boffs = (int*)p;        p += 1024 * sizeof(int);
  int* csr = (int*)p;          p += (size_t)2 * E * sizeof(int);

  hipMemsetAsync(cnt, 0, (size_t)nseg * sizeof(int), stream);

  count_edges<<<2048, 256, 0, stream>>>(ea, eb, E, cnt);
  scan_block_sums<<<nblk, 256, 0, stream>>>(cnt, bsums, nseg);
  scan_bsums<<<1, 256, 0, stream>>>(bsums, boffs, nblk);
  scan_final<<<nblk, 256, 0, stream>>>(cnt, boffs, offs, cursor, invc, nseg);
  fill_edges<<<2048, 256, 0, stream>>>(ea, eb, E, cursor, csr);

  const int agg_blocks = (nseg + 3) / 4;            // 4 waves/block
  const int gemm_blocks = (N + BM - 1) / BM;

  // layer 1
  agg_kernel<<<agg_blocks, 256, 0, stream>>>(x, csr, offs, cnt, invc, agg, nseg);
  fused_gemm<true><<<gemm_blocks, 256, 0, stream>>>(agg, x, W1, root1, b1, hbuf, N);

  // layer 2
  agg_kernel<<<agg_blocks, 256, 0, stream>>>(hbuf, csr, offs, cnt, invc, agg, nseg);
  fused_gemm<false><<<gemm_blocks, 256, 0, stream>>>(agg, hbuf, W2, root2, b2, out, N);
}

// Round 2
// 691.590 us; speedup vs baseline: 1.3517x; 1.3517x over previous
//
#include <hip/hip_runtime.h>
#include <hip/hip_bf16.h>

// RGCN (2 relations, d=128, two layers) for MI355X — round 2.
// Aggregate-then-transform, bf16 MFMA GEMM (16x16x32), no LDS in GEMM.
//   A[n] = [mean_r0 | mean_r1 | x_n]  (384 bf16, contiguous)
//   out[n] = A[n] @ [W0; W1; root] + bias   (one fused GEMM per layer)
// Layer-1 epilogue writes relu(h) bf16 directly into layer-2's A-buffer.

typedef __attribute__((ext_vector_type(8))) short bf16x8;
typedef __attribute__((ext_vector_type(4))) float f32x4;
typedef unsigned short ushort_t;
typedef unsigned int uint_t;

#define NSEG_BLOCK 1024

__device__ __forceinline__ float b2f(ushort_t u) {
  union { uint_t u; float f; } v;
  v.u = (uint_t)u << 16;
  return v.f;
}
__device__ __forceinline__ ushort_t f2b(float f) {
  union { float f; uint_t u; } v;
  v.f = f;
  uint_t u = v.u;
  return (ushort_t)((u + 0x7FFFu + ((u >> 16) & 1u)) >> 16);  // RNE
}

// ---------------- B build: Bt[c][k] = bf16( k<256 ? W[k][c] : root[k-256][c] )
__global__ __launch_bounds__(384) void btbuild(
    const float* __restrict__ W, const float* __restrict__ root,
    ushort_t* __restrict__ Bt) {
  int c = blockIdx.x;
  int k = threadIdx.x;
  float v = (k < 256) ? W[(size_t)k * 128 + c] : root[(size_t)(k - 256) * 128 + c];
  Bt[(size_t)c * 384 + k] = f2b(v);
}

// ---------------- stage x (fp32) -> aggbuf1[n][256..384) bf16
__global__ __launch_bounds__(256) void xstage(
    const float* __restrict__ x, ushort_t* __restrict__ aggbuf, int N) {
  int idx = blockIdx.x * blockDim.x + threadIdx.x;
  int n = idx >> 6, lane = idx & 63;
  if (n >= N) return;
  float2 v = *(const float2*)(x + (size_t)n * 128 + lane * 2);
  uint_t pk = (uint_t)f2b(v.x) | ((uint_t)f2b(v.y) << 16);
  *(uint_t*)(aggbuf + (size_t)n * 384 + 256 + lane * 2) = pk;
}

// ---------------- CSR build ----------------
__global__ __launch_bounds__(256) void count_edges(
    const int* __restrict__ ea, const int* __restrict__ eb,
    int E, int* __restrict__ cnt) {
  int total = 2 * E;
  for (int i = blockIdx.x * blockDim.x + threadIdx.x; i < total;
       i += gridDim.x * blockDim.x) {
    int seg;
    if (i < E) seg = ea[E + i] * 2;
    else       seg = eb[E + (i - E)] * 2 + 1;
    atomicAdd(&cnt[seg], 1);
  }
}

__global__ __launch_bounds__(256) void scan_block_sums(
    const int* __restrict__ cnt, int* __restrict__ bsums, int nseg) {
  __shared__ int sdata[256];
  int base = blockIdx.x * NSEG_BLOCK;
  int s = 0;
#pragma unroll
  for (int j = 0; j < 4; ++j) {
    int i = base + threadIdx.x * 4 + j;
    if (i < nseg) s += cnt[i];
  }
  sdata[threadIdx.x] = s;
  __syncthreads();
  for (int off = 128; off > 0; off >>= 1) {
    if (threadIdx.x < off) sdata[threadIdx.x] += sdata[threadIdx.x + off];
    __syncthreads();
  }
  if (threadIdx.x == 0) bsums[blockIdx.x] = sdata[0];
}

__global__ __launch_bounds__(256) void scan_bsums(
    const int* __restrict__ bsums, int* __restrict__ boffs, int nblk) {
  __shared__ int sdata[256];
  int v = (threadIdx.x < nblk) ? bsums[threadIdx.x] : 0;
  sdata[threadIdx.x] = v;
  __syncthreads();
  for (int off = 1; off < 256; off <<= 1) {
    int t = (threadIdx.x >= (unsigned)off) ? sdata[threadIdx.x - off] : 0;
    __syncthreads();
    sdata[threadIdx.x] += t;
    __syncthreads();
  }
  if (threadIdx.x < nblk) boffs[threadIdx.x] = sdata[threadIdx.x] - v;
}

__global__ __launch_bounds__(256) void scan_final(
    const int* __restrict__ cnt, const int* __restrict__ boffs,
    int* __restrict__ offs, int* __restrict__ cursor, int nseg) {
  __shared__ int sdata[256];
  int base = blockIdx.x * NSEG_BLOCK;
  int loc[4];
  int s = 0;
#pragma unroll
  for (int j = 0; j < 4; ++j) {
    int i = base + threadIdx.x * 4 + j;
    int c = (i < nseg) ? cnt[i] : 0;
    loc[j] = s;
    s += c;
  }
  sdata[threadIdx.x] = s;
  __syncthreads();
  int inc = s;
  for (int off = 1; off < 256; off <<= 1) {
    int t = (threadIdx.x >= (unsigned)off) ? sdata[threadIdx.x - off] : 0;
    __syncthreads();
    sdata[threadIdx.x] += t;
    __syncthreads();
  }
  int excl = sdata[threadIdx.x] - inc + boffs[blockIdx.x];
#pragma unroll
  for (int j = 0; j < 4; ++j) {
    int i = base + threadIdx.x * 4 + j;
    if (i < nseg) {
      int o = excl + loc[j];
      offs[i] = o;
      cursor[i] = o;
    }
  }
}

__global__ __launch_bounds__(256) void fill_edges(
    const int* __restrict__ ea, const int* __restrict__ eb,
    int E, int* __restrict__ cursor, int* __restrict__ csr) {
  int total = 2 * E;
  for (int i = blockIdx.x * blockDim.x + threadIdx.x; i < total;
       i += gridDim.x * blockDim.x) {
    int src, seg;
    if (i < E) { src = ea[i];     seg = ea[E + i] * 2; }
    else       { src = eb[i - E]; seg = eb[E + (i - E)] * 2 + 1; }
    int pos = atomicAdd(&cursor[seg], 1);
    csr[pos] = src;
  }
}

// ---------------- aggregation: one wave per (node, relation) segment -------
// reads bf16 rows at xb[n*384 + 256 ..], writes mean bf16 to agg[n*384 + r*128 ..]
__global__ __launch_bounds__(256) void agg_kernel(
    const ushort_t* __restrict__ xb,
    const int* __restrict__ csr,
    const int* __restrict__ offs, const int* __restrict__ ends,
    ushort_t* __restrict__ agg, int nseg) {
  int wid = (blockIdx.x * blockDim.x + threadIdx.x) >> 6;
  int lane = threadIdx.x & 63;
  if (wid >= nseg) return;
  int beg = offs[wid], end = ends[wid];
  float ax = 0.f, ay = 0.f;
  for (int e = beg; e < end; ++e) {
    int s = csr[e];
    uint_t v = *(const uint_t*)(xb + (size_t)s * 384 + 256 + lane * 2);
    ax += b2f((ushort_t)(v & 0xffffu));
    ay += b2f((ushort_t)(v >> 16));
  }
  int c = end - beg;
  float inv = 1.0f / (float)(c > 1 ? c : 1);
  uint_t pk = (uint_t)f2b(ax * inv) | ((uint_t)f2b(ay * inv) << 16);
  int n = wid >> 1, r = wid & 1;
  *(uint_t*)(agg + (size_t)n * 384 + r * 128 + lane * 2) = pk;
}

// ---------------- MFMA GEMM: [M x 384] bf16 @ [384 x 128] bf16 -> f32 ------
// Block = 4 waves, 128 rows (wave w: rows w*32..w*32+31, all 128 cols).
// MODE 0: out fp32 [M][128] + bias.  MODE 1: relu(out+bias) bf16 into
//         outb[row*384 + 256 + col] (layer-2 A-buffer x-slot).
template <int MODE>
__global__ __launch_bounds__(256) void mfma_gemm(
    const ushort_t* __restrict__ A,   // [Mpad][384]
    const ushort_t* __restrict__ Bt,  // [128][384]
    const float* __restrict__ bias,   // [128]
    float* __restrict__ outf,
    ushort_t* __restrict__ outb,
    int M) {
  const int lane = threadIdx.x & 63;
  const int wave = threadIdx.x >> 6;
  const int lrow = lane & 15;
  const int kg = lane >> 4;
  const int rowbase = blockIdx.x * 128 + wave * 32;

  f32x4 acc[2][8];
#pragma unroll
  for (int i = 0; i < 2; ++i)
#pragma unroll
    for (int c = 0; c < 8; ++c) acc[i][c] = (f32x4){0.f, 0.f, 0.f, 0.f};

  const ushort_t* arow0 = A + (size_t)(rowbase + lrow) * 384 + kg * 8;
  const ushort_t* arow1 = arow0 + (size_t)16 * 384;
  const ushort_t* brow = Bt + (size_t)lrow * 384 + kg * 8;

  for (int kb = 0; kb < 384; kb += 32) {
    bf16x8 a0 = *(const bf16x8*)(arow0 + kb);
    bf16x8 a1 = *(const bf16x8*)(arow1 + kb);
#pragma unroll
    for (int c = 0; c < 8; ++c) {
      bf16x8 b = *(const bf16x8*)(brow + (size_t)c * 16 * 384 + kb);
      acc[0][c] = __builtin_amdgcn_mfma_f32_16x16x32_bf16(a0, b, acc[0][c], 0, 0, 0);
      acc[1][c] = __builtin_amdgcn_mfma_f32_16x16x32_bf16(a1, b, acc[1][c], 0, 0, 0);
    }
  }

#pragma unroll
  for (int c = 0; c < 8; ++c) {
    int col = c * 16 + lrow;
    float bv = bias[col];
#pragma unroll
    for (int i = 0; i < 2; ++i) {
      int r0 = rowbase + i * 16 + kg * 4;
#pragma unroll
      for (int r = 0; r < 4; ++r) {
        int row = r0 + r;
        if (row < M) {
          float v = acc[i][c][r] + bv;
          if (MODE == 1) {
            v = fmaxf(v, 0.f);
            outb[(size_t)row * 384 + 256 + col] = f2b(v);
          } else {
            outf[(size_t)row * 128 + col] = v;
          }
        }
      }
    }
  }
}

// ---------------- launch ----------------
extern "C" void kernel_launch(void* const* d_in, const int* in_sizes, int n_in,
                              void* d_out, int out_size, void* d_ws, size_t ws_size,
                              hipStream_t stream) {
  const float* x     = (const float*)d_in[0];
  const int*   ea    = (const int*)d_in[1];
  const int*   eb    = (const int*)d_in[2];
  const float* W1    = (const float*)d_in[3];
  const float* root1 = (const float*)d_in[4];
  const float* b1    = (const float*)d_in[5];
  const float* W2    = (const float*)d_in[6];
  const float* root2 = (const float*)d_in[7];
  const float* b2    = (const float*)d_in[8];
  float* out = (float*)d_out;

  const int N = in_sizes[0] / 128;
  const int E = in_sizes[1] / 2;
  const int nseg = N * 2;
  const int nblk = (nseg + NSEG_BLOCK - 1) / NSEG_BLOCK;
  const int Mblk = (N + 127) / 128;
  const int Mpad = Mblk * 128;

  // workspace carve-up (all 16B-aligned)
  char* p = (char*)d_ws;
  ushort_t* aggbuf1 = (ushort_t*)p;  p += (size_t)Mpad * 384 * sizeof(ushort_t);
  ushort_t* aggbuf2 = (ushort_t*)p;  p += (size_t)Mpad * 384 * sizeof(ushort_t);
  ushort_t* Bt1 = (ushort_t*)p;      p += (size_t)128 * 384 * sizeof(ushort_t);
  ushort_t* Bt2 = (ushort_t*)p;      p += (size_t)128 * 384 * sizeof(ushort_t);
  int* cnt = (int*)p;                p += (size_t)nseg * sizeof(int);
  int* offs = (int*)p;               p += (size_t)nseg * sizeof(int);
  int* cursor = (int*)p;             p += (size_t)nseg * sizeof(int);
  int* bsums = (int*)p;              p += 1024 * sizeof(int);
  int* boffs = (int*)p;              p += 1024 * sizeof(int);
  int* csr = (int*)p;                p += (size_t)2 * E * sizeof(int);

  hipMemsetAsync(cnt, 0, (size_t)nseg * sizeof(int), stream);

  btbuild<<<128, 384, 0, stream>>>(W1, root1, Bt1);
  btbuild<<<128, 384, 0, stream>>>(W2, root2, Bt2);
  xstage<<<(N * 64 + 255) / 256, 256, 0, stream>>>(x, aggbuf1, N);

  count_edges<<<2048, 256, 0, stream>>>(ea, eb, E, cnt);
  scan_block_sums<<<nblk, 256, 0, stream>>>(cnt, bsums, nseg);
  scan_bsums<<<1, 256, 0, stream>>>(bsums, boffs, nblk);
  scan_final<<<nblk, 256, 0, stream>>>(cnt, boffs, offs, cursor, nseg);
  fill_edges<<<2048, 256, 0, stream>>>(ea, eb, E, cursor, csr);

  const int agg_blocks = (nseg + 3) / 4;  // 4 waves/block

  // layer 1
  agg_kernel<<<agg_blocks, 256, 0, stream>>>(aggbuf1, csr, offs, cursor, aggbuf1, nseg);
  mfma_gemm<1><<<Mblk, 256, 0, stream>>>(aggbuf1, Bt1, b1, nullptr, aggbuf2, N);

  // layer 2
  agg_kernel<<<agg_blocks, 256, 0, stream>>>(aggbuf2, csr, offs, cursor, aggbuf2, nseg);
  mfma_gemm<0><<<Mblk, 256, 0, stream>>>(aggbuf2, Bt2, b2, out, nullptr, N);
}

// Round 3
// 523.762 us; speedup vs baseline: 1.7849x; 1.3204x over previous
//
#include <hip/hip_runtime.h>
#include <hip/hip_bf16.h>

// RGCN (2 relations, d=128, two layers) for MI355X — round 3.
// Aggregate-then-transform, bf16 MFMA GEMM (16x16x32), no LDS in GEMM.
//   A[n] = [mean_r0 | mean_r1 | x_n]  (384 bf16, contiguous)
//   out[n] = A[n] @ [W0; W1; root] + bias   (one fused GEMM per layer)
// Layer-1 epilogue writes relu(h) bf16 directly into layer-2's A-buffer.
// Round-3 change: agg_kernel quarter-wave-per-edge (4 edges in flight,
// x2 manual unroll -> 8 rows outstanding) to break the latency chain.

typedef __attribute__((ext_vector_type(8))) short bf16x8;
typedef __attribute__((ext_vector_type(4))) float f32x4;
typedef unsigned short ushort_t;
typedef unsigned int uint_t;

#define NSEG_BLOCK 1024

__device__ __forceinline__ float b2f(ushort_t u) {
  union { uint_t u; float f; } v;
  v.u = (uint_t)u << 16;
  return v.f;
}
__device__ __forceinline__ float b2fu(uint_t u) {  // low 16 bits -> float
  union { uint_t u; float f; } v;
  v.u = u << 16;
  return v.f;
}
__device__ __forceinline__ ushort_t f2b(float f) {
  union { float f; uint_t u; } v;
  v.f = f;
  uint_t u = v.u;
  return (ushort_t)((u + 0x7FFFu + ((u >> 16) & 1u)) >> 16);  // RNE
}

// ---------------- B build: Bt[c][k] = bf16( k<256 ? W[k][c] : root[k-256][c] )
__global__ __launch_bounds__(384) void btbuild(
    const float* __restrict__ W, const float* __restrict__ root,
    ushort_t* __restrict__ Bt) {
  int c = blockIdx.x;
  int k = threadIdx.x;
  float v = (k < 256) ? W[(size_t)k * 128 + c] : root[(size_t)(k - 256) * 128 + c];
  Bt[(size_t)c * 384 + k] = f2b(v);
}

// ---------------- stage x (fp32) -> aggbuf1[n][256..384) bf16
__global__ __launch_bounds__(256) void xstage(
    const float* __restrict__ x, ushort_t* __restrict__ aggbuf, int N) {
  int idx = blockIdx.x * blockDim.x + threadIdx.x;
  int n = idx >> 6, lane = idx & 63;
  if (n >= N) return;
  float2 v = *(const float2*)(x + (size_t)n * 128 + lane * 2);
  uint_t pk = (uint_t)f2b(v.x) | ((uint_t)f2b(v.y) << 16);
  *(uint_t*)(aggbuf + (size_t)n * 384 + 256 + lane * 2) = pk;
}

// ---------------- CSR build ----------------
__global__ __launch_bounds__(256) void count_edges(
    const int* __restrict__ ea, const int* __restrict__ eb,
    int E, int* __restrict__ cnt) {
  int total = 2 * E;
  for (int i = blockIdx.x * blockDim.x + threadIdx.x; i < total;
       i += gridDim.x * blockDim.x) {
    int seg;
    if (i < E) seg = ea[E + i] * 2;
    else       seg = eb[E + (i - E)] * 2 + 1;
    atomicAdd(&cnt[seg], 1);
  }
}

__global__ __launch_bounds__(256) void scan_block_sums(
    const int* __restrict__ cnt, int* __restrict__ bsums, int nseg) {
  __shared__ int sdata[256];
  int base = blockIdx.x * NSEG_BLOCK;
  int s = 0;
#pragma unroll
  for (int j = 0; j < 4; ++j) {
    int i = base + threadIdx.x * 4 + j;
    if (i < nseg) s += cnt[i];
  }
  sdata[threadIdx.x] = s;
  __syncthreads();
  for (int off = 128; off > 0; off >>= 1) {
    if (threadIdx.x < off) sdata[threadIdx.x] += sdata[threadIdx.x + off];
    __syncthreads();
  }
  if (threadIdx.x == 0) bsums[blockIdx.x] = sdata[0];
}

__global__ __launch_bounds__(256) void scan_bsums(
    const int* __restrict__ bsums, int* __restrict__ boffs, int nblk) {
  __shared__ int sdata[256];
  int v = (threadIdx.x < nblk) ? bsums[threadIdx.x] : 0;
  sdata[threadIdx.x] = v;
  __syncthreads();
  for (int off = 1; off < 256; off <<= 1) {
    int t = (threadIdx.x >= (unsigned)off) ? sdata[threadIdx.x - off] : 0;
    __syncthreads();
    sdata[threadIdx.x] += t;
    __syncthreads();
  }
  if (threadIdx.x < nblk) boffs[threadIdx.x] = sdata[threadIdx.x] - v;
}

__global__ __launch_bounds__(256) void scan_final(
    const int* __restrict__ cnt, const int* __restrict__ boffs,
    int* __restrict__ offs, int* __restrict__ cursor, int nseg) {
  __shared__ int sdata[256];
  int base = blockIdx.x * NSEG_BLOCK;
  int loc[4];
  int s = 0;
#pragma unroll
  for (int j = 0; j < 4; ++j) {
    int i = base + threadIdx.x * 4 + j;
    int c = (i < nseg) ? cnt[i] : 0;
    loc[j] = s;
    s += c;
  }
  sdata[threadIdx.x] = s;
  __syncthreads();
  int inc = s;
  for (int off = 1; off < 256; off <<= 1) {
    int t = (threadIdx.x >= (unsigned)off) ? sdata[threadIdx.x - off] : 0;
    __syncthreads();
    sdata[threadIdx.x] += t;
    __syncthreads();
  }
  int excl = sdata[threadIdx.x] - inc + boffs[blockIdx.x];
#pragma unroll
  for (int j = 0; j < 4; ++j) {
    int i = base + threadIdx.x * 4 + j;
    if (i < nseg) {
      int o = excl + loc[j];
      offs[i] = o;
      cursor[i] = o;
    }
  }
}

__global__ __launch_bounds__(256) void fill_edges(
    const int* __restrict__ ea, const int* __restrict__ eb,
    int E, int* __restrict__ cursor, int* __restrict__ csr) {
  int total = 2 * E;
  for (int i = blockIdx.x * blockDim.x + threadIdx.x; i < total;
       i += gridDim.x * blockDim.x) {
    int src, seg;
    if (i < E) { src = ea[i];     seg = ea[E + i] * 2; }
    else       { src = eb[i - E]; seg = eb[E + (i - E)] * 2 + 1; }
    int pos = atomicAdd(&cursor[seg], 1);
    csr[pos] = src;
  }
}

// ---------------- aggregation: one wave per segment, quarter-wave per edge --
// bf16 row = 256 B = 16 lanes x uint4. 4 edges in flight, unroll x2 -> 8.
__device__ __forceinline__ void accum8(float* acc, uint4 v) {
  acc[0] += b2fu(v.x); acc[1] += b2fu(v.x >> 16);
  acc[2] += b2fu(v.y); acc[3] += b2fu(v.y >> 16);
  acc[4] += b2fu(v.z); acc[5] += b2fu(v.z >> 16);
  acc[6] += b2fu(v.w); acc[7] += b2fu(v.w >> 16);
}

__global__ __launch_bounds__(256) void agg_kernel(
    const ushort_t* __restrict__ xb,   // rows at xb[n*384 + 256 ..]
    const int* __restrict__ csr,
    const int* __restrict__ offs, const int* __restrict__ ends,
    ushort_t* __restrict__ agg, int nseg) {
  int wid = (blockIdx.x * blockDim.x + threadIdx.x) >> 6;
  if (wid >= nseg) return;
  int lane = threadIdx.x & 63;
  int q = lane >> 4;   // quarter-wave id: which edge in group of 4
  int t = lane & 15;   // 16 lanes x 16 B = one 256 B row
  int beg = offs[wid], end = ends[wid];

  float acc[8];
#pragma unroll
  for (int j = 0; j < 8; ++j) acc[j] = 0.f;

  int e = beg + q;
  for (; e + 4 < end; e += 8) {
    int s0 = csr[e];
    int s1 = csr[e + 4];
    uint4 v0 = *(const uint4*)(xb + (size_t)s0 * 384 + 256 + t * 8);
    uint4 v1 = *(const uint4*)(xb + (size_t)s1 * 384 + 256 + t * 8);
    accum8(acc, v0);
    accum8(acc, v1);
  }
  if (e < end) {
    int s0 = csr[e];
    uint4 v0 = *(const uint4*)(xb + (size_t)s0 * 384 + 256 + t * 8);
    accum8(acc, v0);
  }

  // combine the 4 quarter-wave partial sums (lanes xor 16, xor 32)
#pragma unroll
  for (int j = 0; j < 8; ++j) {
    acc[j] += __shfl_xor(acc[j], 16);
    acc[j] += __shfl_xor(acc[j], 32);
  }

  int c = end - beg;
  float inv = 1.0f / (float)(c > 1 ? c : 1);
  if (q == 0) {
    uint4 o;
    o.x = (uint_t)f2b(acc[0] * inv) | ((uint_t)f2b(acc[1] * inv) << 16);
    o.y = (uint_t)f2b(acc[2] * inv) | ((uint_t)f2b(acc[3] * inv) << 16);
    o.z = (uint_t)f2b(acc[4] * inv) | ((uint_t)f2b(acc[5] * inv) << 16);
    o.w = (uint_t)f2b(acc[6] * inv) | ((uint_t)f2b(acc[7] * inv) << 16);
    int n = wid >> 1, r = wid & 1;
    *(uint4*)(agg + (size_t)n * 384 + r * 128 + t * 8) = o;
  }
}

// ---------------- MFMA GEMM: [M x 384] bf16 @ [384 x 128] bf16 -> f32 ------
// Block = 4 waves, 128 rows (wave w: rows w*32..w*32+31, all 128 cols).
// MODE 0: out fp32 [M][128] + bias.  MODE 1: relu(out+bias) bf16 into
//         outb[row*384 + 256 + col] (layer-2 A-buffer x-slot).
template <int MODE>
__global__ __launch_bounds__(256) void mfma_gemm(
    const ushort_t* __restrict__ A,   // [Mpad][384]
    const ushort_t* __restrict__ Bt,  // [128][384]
    const float* __restrict__ bias,   // [128]
    float* __restrict__ outf,
    ushort_t* __restrict__ outb,
    int M) {
  const int lane = threadIdx.x & 63;
  const int wave = threadIdx.x >> 6;
  const int lrow = lane & 15;
  const int kg = lane >> 4;
  const int rowbase = blockIdx.x * 128 + wave * 32;

  f32x4 acc[2][8];
#pragma unroll
  for (int i = 0; i < 2; ++i)
#pragma unroll
    for (int c = 0; c < 8; ++c) acc[i][c] = (f32x4){0.f, 0.f, 0.f, 0.f};

  const ushort_t* arow0 = A + (size_t)(rowbase + lrow) * 384 + kg * 8;
  const ushort_t* arow1 = arow0 + (size_t)16 * 384;
  const ushort_t* brow = Bt + (size_t)lrow * 384 + kg * 8;

  for (int kb = 0; kb < 384; kb += 32) {
    bf16x8 a0 = *(const bf16x8*)(arow0 + kb);
    bf16x8 a1 = *(const bf16x8*)(arow1 + kb);
#pragma unroll
    for (int c = 0; c < 8; ++c) {
      bf16x8 b = *(const bf16x8*)(brow + (size_t)c * 16 * 384 + kb);
      acc[0][c] = __builtin_amdgcn_mfma_f32_16x16x32_bf16(a0, b, acc[0][c], 0, 0, 0);
      acc[1][c] = __builtin_amdgcn_mfma_f32_16x16x32_bf16(a1, b, acc[1][c], 0, 0, 0);
    }
  }

#pragma unroll
  for (int c = 0; c < 8; ++c) {
    int col = c * 16 + lrow;
    float bv = bias[col];
#pragma unroll
    for (int i = 0; i < 2; ++i) {
      int r0 = rowbase + i * 16 + kg * 4;
#pragma unroll
      for (int r = 0; r < 4; ++r) {
        int row = r0 + r;
        if (row < M) {
          float v = acc[i][c][r] + bv;
          if (MODE == 1) {
            v = fmaxf(v, 0.f);
            outb[(size_t)row * 384 + 256 + col] = f2b(v);
          } else {
            outf[(size_t)row * 128 + col] = v;
          }
        }
      }
    }
  }
}

// ---------------- launch ----------------
extern "C" void kernel_launch(void* const* d_in, const int* in_sizes, int n_in,
                              void* d_out, int out_size, void* d_ws, size_t ws_size,
                              hipStream_t stream) {
  const float* x     = (const float*)d_in[0];
  const int*   ea    = (const int*)d_in[1];
  const int*   eb    = (const int*)d_in[2];
  const float* W1    = (const float*)d_in[3];
  const float* root1 = (const float*)d_in[4];
  const float* b1    = (const float*)d_in[5];
  const float* W2    = (const float*)d_in[6];
  const float* root2 = (const float*)d_in[7];
  const float* b2    = (const float*)d_in[8];
  float* out = (float*)d_out;

  const int N = in_sizes[0] / 128;
  const int E = in_sizes[1] / 2;
  const int nseg = N * 2;
  const int nblk = (nseg + NSEG_BLOCK - 1) / NSEG_BLOCK;
  const int Mblk = (N + 127) / 128;
  const int Mpad = Mblk * 128;

  // workspace carve-up (all 16B-aligned)
  char* p = (char*)d_ws;
  ushort_t* aggbuf1 = (ushort_t*)p;  p += (size_t)Mpad * 384 * sizeof(ushort_t);
  ushort_t* aggbuf2 = (ushort_t*)p;  p += (size_t)Mpad * 384 * sizeof(ushort_t);
  ushort_t* Bt1 = (ushort_t*)p;      p += (size_t)128 * 384 * sizeof(ushort_t);
  ushort_t* Bt2 = (ushort_t*)p;      p += (size_t)128 * 384 * sizeof(ushort_t);
  int* cnt = (int*)p;                p += (size_t)nseg * sizeof(int);
  int* offs = (int*)p;               p += (size_t)nseg * sizeof(int);
  int* cursor = (int*)p;             p += (size_t)nseg * sizeof(int);
  int* bsums = (int*)p;              p += 1024 * sizeof(int);
  int* boffs = (int*)p;              p += 1024 * sizeof(int);
  int* csr = (int*)p;                p += (size_t)2 * E * sizeof(int);

  hipMemsetAsync(cnt, 0, (size_t)nseg * sizeof(int), stream);

  btbuild<<<128, 384, 0, stream>>>(W1, root1, Bt1);
  btbuild<<<128, 384, 0, stream>>>(W2, root2, Bt2);
  xstage<<<(N * 64 + 255) / 256, 256, 0, stream>>>(x, aggbuf1, N);

  count_edges<<<2048, 256, 0, stream>>>(ea, eb, E, cnt);
  scan_block_sums<<<nblk, 256, 0, stream>>>(cnt, bsums, nseg);
  scan_bsums<<<1, 256, 0, stream>>>(bsums, boffs, nblk);
  scan_final<<<nblk, 256, 0, stream>>>(cnt, boffs, offs, cursor, nseg);
  fill_edges<<<2048, 256, 0, stream>>>(ea, eb, E, cursor, csr);

  const int agg_blocks = (nseg + 3) / 4;  // 4 waves/block, 1 wave/segment

  // layer 1
  agg_kernel<<<agg_blocks, 256, 0, stream>>>(aggbuf1, csr, offs, cursor, aggbuf1, nseg);
  mfma_gemm<1><<<Mblk, 256, 0, stream>>>(aggbuf1, Bt1, b1, nullptr, aggbuf2, N);

  // layer 2
  agg_kernel<<<agg_blocks, 256, 0, stream>>>(aggbuf2, csr, offs, cursor, aggbuf2, nseg);
  mfma_gemm<0><<<Mblk, 256, 0, stream>>>(aggbuf2, Bt2, b2, out, nullptr, N);
}

// Round 4
// 381.072 us; speedup vs baseline: 2.4532x; 1.3744x over previous
//
#include <hip/hip_runtime.h>
#include <hip/hip_bf16.h>

// RGCN (2 relations, d=128, two layers) for MI355X — round 4.
// Aggregate-then-transform, bf16 MFMA GEMM (16x16x32), no LDS in GEMM.
//   A[n] = [mean_r0 | mean_r1 | x_n]  (384 bf16, contiguous)
//   out[n] = A[n] @ [W0; W1; root] + bias   (one fused GEMM per layer)
// Round-4 change: CSR build rewritten as 2-level bucketed counting sort
// (bucket = dst>>9) so all scatter writes land in per-bucket contiguous
// regions -> full-line L2 write merging (kills the 16x write amplification
// of the old atomic-cursor fill_edges).

typedef __attribute__((ext_vector_type(8))) short bf16x8;
typedef __attribute__((ext_vector_type(4))) float f32x4;
typedef unsigned short ushort_t;
typedef unsigned int uint_t;

#define BSHIFT 9                      // bucket = dst >> 9 (512 nodes/bucket)
#define SEGB (1 << (BSHIFT + 1))      // 1024 segments per bucket
#define NBMAX 256
#define CH_PER_THREAD 16
#define CHUNK (256 * CH_PER_THREAD)   // 4096 edges per bin block

__device__ __forceinline__ float b2fu(uint_t u) {  // low 16 bits -> float
  union { uint_t u; float f; } v;
  v.u = u << 16;
  return v.f;
}
__device__ __forceinline__ ushort_t f2b(float f) {
  union { float f; uint_t u; } v;
  v.f = f;
  uint_t u = v.u;
  return (ushort_t)((u + 0x7FFFu + ((u >> 16) & 1u)) >> 16);  // RNE
}

// ---------------- B build: Bt[c][k] = bf16( k<256 ? W[k][c] : root[k-256][c] )
__global__ __launch_bounds__(384) void btbuild(
    const float* __restrict__ W, const float* __restrict__ root,
    ushort_t* __restrict__ Bt) {
  int c = blockIdx.x;
  int k = threadIdx.x;
  float v = (k < 256) ? W[(size_t)k * 128 + c] : root[(size_t)(k - 256) * 128 + c];
  Bt[(size_t)c * 384 + k] = f2b(v);
}

// ---------------- stage x (fp32) -> aggbuf1[n][256..384) bf16
__global__ __launch_bounds__(256) void xstage(
    const float* __restrict__ x, ushort_t* __restrict__ aggbuf, int N) {
  int idx = blockIdx.x * blockDim.x + threadIdx.x;
  int n = idx >> 6, lane = idx & 63;
  if (n >= N) return;
  float2 v = *(const float2*)(x + (size_t)n * 128 + lane * 2);
  uint_t pk = (uint_t)f2b(v.x) | ((uint_t)f2b(v.y) << 16);
  *(uint_t*)(aggbuf + (size_t)n * 384 + 256 + lane * 2) = pk;
}

// ---------------- CSR build: bucketed counting sort ----------------
// stage A: per-bucket histogram
__global__ __launch_bounds__(256) void bucket_hist(
    const int* __restrict__ ea, const int* __restrict__ eb,
    int E, int NB, int* __restrict__ bucket_cnt) {
  __shared__ int h[NBMAX];
  for (int i = threadIdx.x; i < NB; i += 256) h[i] = 0;
  __syncthreads();
  int tbase = blockIdx.x * CHUNK + threadIdx.x;
  int total = 2 * E;
#pragma unroll
  for (int j = 0; j < CH_PER_THREAD; ++j) {
    int i = tbase + j * 256;
    if (i < total) {
      int dst = (i < E) ? ea[E + i] : eb[i];
      atomicAdd(&h[dst >> BSHIFT], 1);
    }
  }
  __syncthreads();
  for (int i = threadIdx.x; i < NB; i += 256)
    if (h[i]) atomicAdd(&bucket_cnt[i], h[i]);
}

// stage A2: exclusive scan of bucket counts (NB <= 256, one block)
__global__ __launch_bounds__(256) void bucket_scan(
    const int* __restrict__ bucket_cnt, int* __restrict__ bucket_base,
    int* __restrict__ bucket_cursor, int NB) {
  __shared__ int sdata[256];
  int v = (threadIdx.x < NB) ? bucket_cnt[threadIdx.x] : 0;
  sdata[threadIdx.x] = v;
  __syncthreads();
  for (int off = 1; off < 256; off <<= 1) {
    int t = (threadIdx.x >= (unsigned)off) ? sdata[threadIdx.x - off] : 0;
    __syncthreads();
    sdata[threadIdx.x] += t;
    __syncthreads();
  }
  if (threadIdx.x < NB) {
    int e = sdata[threadIdx.x] - v;
    bucket_base[threadIdx.x] = e;
    bucket_cursor[threadIdx.x] = e;
  }
}

// stage B: bin {src, seg} records into per-bucket contiguous staging runs
__global__ __launch_bounds__(256) void bucket_bin(
    const int* __restrict__ ea, const int* __restrict__ eb,
    int E, int NB, int* __restrict__ bucket_cursor,
    uint2* __restrict__ staging) {
  __shared__ int h[NBMAX];
  __shared__ int bbase[NBMAX];
  for (int i = threadIdx.x; i < NB; i += 256) h[i] = 0;
  __syncthreads();
  int tbase = blockIdx.x * CHUNK + threadIdx.x;
  int total = 2 * E;
  uint2 val[CH_PER_THREAD];
#pragma unroll
  for (int j = 0; j < CH_PER_THREAD; ++j) {
    int i = tbase + j * 256;
    if (i < total) {
      int src, dst, rel;
      if (i < E) { src = ea[i];     dst = ea[E + i]; rel = 0; }
      else       { src = eb[i - E]; dst = eb[i];     rel = 1; }
      val[j].x = (uint_t)src;
      val[j].y = (uint_t)(dst * 2 + rel);
      atomicAdd(&h[dst >> BSHIFT], 1);
    } else {
      val[j].y = 0xffffffffu;
    }
  }
  __syncthreads();
  for (int i = threadIdx.x; i < NB; i += 256) {
    int c = h[i];
    bbase[i] = c ? atomicAdd(&bucket_cursor[i], c) : 0;
    h[i] = 0;
  }
  __syncthreads();
#pragma unroll
  for (int j = 0; j < CH_PER_THREAD; ++j) {
    if (val[j].y != 0xffffffffu) {
      int bkt = (int)(val[j].y >> (BSHIFT + 1));
      int r = atomicAdd(&h[bkt], 1);
      staging[(size_t)bbase[bkt] + r] = val[j];
    }
  }
}

// stage C: per-bucket segment hist + scan + scatter into contiguous csr range
__global__ __launch_bounds__(256) void bucket_build(
    const uint2* __restrict__ staging,
    const int* __restrict__ bucket_base, const int* __restrict__ bucket_cnt,
    int* __restrict__ csr, int* __restrict__ offs, int* __restrict__ ends,
    int nseg) {
  __shared__ int scnt[SEGB];
  __shared__ int sexcl[SEGB];
  __shared__ int sdata[256];
  int b = blockIdx.x;
  int base = bucket_base[b];
  int ne = bucket_cnt[b];
  int seg0 = b << (BSHIFT + 1);
  int t = threadIdx.x;
  for (int i = t; i < SEGB; i += 256) scnt[i] = 0;
  __syncthreads();
  const uint2* st = staging + base;
  for (int i = t; i < ne; i += 256) {
    int seg = (int)st[i].y - seg0;
    atomicAdd(&scnt[seg], 1);
  }
  __syncthreads();
  // exclusive scan of scnt[0..1024): 4 per thread + Hillis-Steele on partials
  int c0 = scnt[t * 4 + 0], c1 = scnt[t * 4 + 1];
  int c2 = scnt[t * 4 + 2], c3 = scnt[t * 4 + 3];
  int s = c0 + c1 + c2 + c3;
  sdata[t] = s;
  __syncthreads();
  for (int off = 1; off < 256; off <<= 1) {
    int tmp = (t >= (unsigned)off) ? sdata[t - off] : 0;
    __syncthreads();
    sdata[t] += tmp;
    __syncthreads();
  }
  int excl = sdata[t] - s;
  int e0 = excl, e1 = excl + c0, e2 = e1 + c1, e3 = e2 + c2;
  sexcl[t * 4 + 0] = e0;
  sexcl[t * 4 + 1] = e1;
  sexcl[t * 4 + 2] = e2;
  sexcl[t * 4 + 3] = e3;
  // global offs/ends
  {
    int g = seg0 + t * 4;
    if (g + 0 < nseg) { offs[g + 0] = base + e0; ends[g + 0] = base + e0 + c0; }
    if (g + 1 < nseg) { offs[g + 1] = base + e1; ends[g + 1] = base + e1 + c1; }
    if (g + 2 < nseg) { offs[g + 2] = base + e2; ends[g + 2] = base + e2 + c2; }
    if (g + 3 < nseg) { offs[g + 3] = base + e3; ends[g + 3] = base + e3 + c3; }
  }
  // reset own counters for ranking
  scnt[t * 4 + 0] = 0;
  scnt[t * 4 + 1] = 0;
  scnt[t * 4 + 2] = 0;
  scnt[t * 4 + 3] = 0;
  __syncthreads();
  for (int i = t; i < ne; i += 256) {
    uint2 v = st[i];
    int seg = (int)v.y - seg0;
    int r = atomicAdd(&scnt[seg], 1);
    csr[base + sexcl[seg] + r] = (int)v.x;
  }
}

// ---------------- aggregation: one wave per segment, quarter-wave per edge --
__device__ __forceinline__ void accum8(float* acc, uint4 v) {
  acc[0] += b2fu(v.x); acc[1] += b2fu(v.x >> 16);
  acc[2] += b2fu(v.y); acc[3] += b2fu(v.y >> 16);
  acc[4] += b2fu(v.z); acc[5] += b2fu(v.z >> 16);
  acc[6] += b2fu(v.w); acc[7] += b2fu(v.w >> 16);
}

__global__ __launch_bounds__(256) void agg_kernel(
    const ushort_t* __restrict__ xb,   // rows at xb[n*384 + 256 ..]
    const int* __restrict__ csr,
    const int* __restrict__ offs, const int* __restrict__ ends,
    ushort_t* __restrict__ agg, int nseg) {
  int wid = (blockIdx.x * blockDim.x + threadIdx.x) >> 6;
  if (wid >= nseg) return;
  int lane = threadIdx.x & 63;
  int q = lane >> 4;   // quarter-wave id: which edge in group of 4
  int t = lane & 15;   // 16 lanes x 16 B = one 256 B row
  int beg = offs[wid], end = ends[wid];

  float acc[8];
#pragma unroll
  for (int j = 0; j < 8; ++j) acc[j] = 0.f;

  int e = beg + q;
  for (; e + 4 < end; e += 8) {
    int s0 = csr[e];
    int s1 = csr[e + 4];
    uint4 v0 = *(const uint4*)(xb + (size_t)s0 * 384 + 256 + t * 8);
    uint4 v1 = *(const uint4*)(xb + (size_t)s1 * 384 + 256 + t * 8);
    accum8(acc, v0);
    accum8(acc, v1);
  }
  if (e < end) {
    int s0 = csr[e];
    uint4 v0 = *(const uint4*)(xb + (size_t)s0 * 384 + 256 + t * 8);
    accum8(acc, v0);
  }

#pragma unroll
  for (int j = 0; j < 8; ++j) {
    acc[j] += __shfl_xor(acc[j], 16);
    acc[j] += __shfl_xor(acc[j], 32);
  }

  int c = end - beg;
  float inv = 1.0f / (float)(c > 1 ? c : 1);
  if (q == 0) {
    uint4 o;
    o.x = (uint_t)f2b(acc[0] * inv) | ((uint_t)f2b(acc[1] * inv) << 16);
    o.y = (uint_t)f2b(acc[2] * inv) | ((uint_t)f2b(acc[3] * inv) << 16);
    o.z = (uint_t)f2b(acc[4] * inv) | ((uint_t)f2b(acc[5] * inv) << 16);
    o.w = (uint_t)f2b(acc[6] * inv) | ((uint_t)f2b(acc[7] * inv) << 16);
    int n = wid >> 1, r = wid & 1;
    *(uint4*)(agg + (size_t)n * 384 + r * 128 + t * 8) = o;
  }
}

// ---------------- MFMA GEMM: [M x 384] bf16 @ [384 x 128] bf16 -> f32 ------
template <int MODE>
__global__ __launch_bounds__(256) void mfma_gemm(
    const ushort_t* __restrict__ A,   // [Mpad][384]
    const ushort_t* __restrict__ Bt,  // [128][384]
    const float* __restrict__ bias,   // [128]
    float* __restrict__ outf,
    ushort_t* __restrict__ outb,
    int M) {
  const int lane = threadIdx.x & 63;
  const int wave = threadIdx.x >> 6;
  const int lrow = lane & 15;
  const int kg = lane >> 4;
  const int rowbase = blockIdx.x * 128 + wave * 32;

  f32x4 acc[2][8];
#pragma unroll
  for (int i = 0; i < 2; ++i)
#pragma unroll
    for (int c = 0; c < 8; ++c) acc[i][c] = (f32x4){0.f, 0.f, 0.f, 0.f};

  const ushort_t* arow0 = A + (size_t)(rowbase + lrow) * 384 + kg * 8;
  const ushort_t* arow1 = arow0 + (size_t)16 * 384;
  const ushort_t* brow = Bt + (size_t)lrow * 384 + kg * 8;

  for (int kb = 0; kb < 384; kb += 32) {
    bf16x8 a0 = *(const bf16x8*)(arow0 + kb);
    bf16x8 a1 = *(const bf16x8*)(arow1 + kb);
#pragma unroll
    for (int c = 0; c < 8; ++c) {
      bf16x8 b = *(const bf16x8*)(brow + (size_t)c * 16 * 384 + kb);
      acc[0][c] = __builtin_amdgcn_mfma_f32_16x16x32_bf16(a0, b, acc[0][c], 0, 0, 0);
      acc[1][c] = __builtin_amdgcn_mfma_f32_16x16x32_bf16(a1, b, acc[1][c], 0, 0, 0);
    }
  }

#pragma unroll
  for (int c = 0; c < 8; ++c) {
    int col = c * 16 + lrow;
    float bv = bias[col];
#pragma unroll
    for (int i = 0; i < 2; ++i) {
      int r0 = rowbase + i * 16 + kg * 4;
#pragma unroll
      for (int r = 0; r < 4; ++r) {
        int row = r0 + r;
        if (row < M) {
          float v = acc[i][c][r] + bv;
          if (MODE == 1) {
            v = fmaxf(v, 0.f);
            outb[(size_t)row * 384 + 256 + col] = f2b(v);
          } else {
            outf[(size_t)row * 128 + col] = v;
          }
        }
      }
    }
  }
}

// ---------------- launch ----------------
extern "C" void kernel_launch(void* const* d_in, const int* in_sizes, int n_in,
                              void* d_out, int out_size, void* d_ws, size_t ws_size,
                              hipStream_t stream) {
  const float* x     = (const float*)d_in[0];
  const int*   ea    = (const int*)d_in[1];
  const int*   eb    = (const int*)d_in[2];
  const float* W1    = (const float*)d_in[3];
  const float* root1 = (const float*)d_in[4];
  const float* b1    = (const float*)d_in[5];
  const float* W2    = (const float*)d_in[6];
  const float* root2 = (const float*)d_in[7];
  const float* b2    = (const float*)d_in[8];
  float* out = (float*)d_out;

  const int N = in_sizes[0] / 128;
  const int E = in_sizes[1] / 2;
  const int nseg = N * 2;
  const int Mblk = (N + 127) / 128;
  const int Mpad = Mblk * 128;
  const int NB = ((N - 1) >> BSHIFT) + 1;         // 196 for N=100000
  const int nchunk = (2 * E + CHUNK - 1) / CHUNK; // 391 for E=800000

  // workspace carve-up (all 16B-aligned)
  char* p = (char*)d_ws;
  ushort_t* aggbuf1 = (ushort_t*)p;  p += (size_t)Mpad * 384 * sizeof(ushort_t);
  ushort_t* aggbuf2 = (ushort_t*)p;  p += (size_t)Mpad * 384 * sizeof(ushort_t);
  ushort_t* Bt1 = (ushort_t*)p;      p += (size_t)128 * 384 * sizeof(ushort_t);
  ushort_t* Bt2 = (ushort_t*)p;      p += (size_t)128 * 384 * sizeof(ushort_t);
  int* csr = (int*)p;                p += (size_t)2 * E * sizeof(int);
  int* offs = (int*)p;               p += (size_t)nseg * sizeof(int);
  int* ends = (int*)p;               p += (size_t)nseg * sizeof(int);
  int* bucket_cnt = (int*)p;         p += NBMAX * sizeof(int);
  int* bucket_base = (int*)p;        p += NBMAX * sizeof(int);
  int* bucket_cursor = (int*)p;      p += NBMAX * sizeof(int);
  // staging (2E uint2 = 12.8 MB) aliases aggbuf2: staging is dead before
  // gemm1/agg2 write aggbuf2, and aggbuf2 is never read before being written.
  uint2* staging = (uint2*)aggbuf2;

  hipMemsetAsync(bucket_cnt, 0, NBMAX * sizeof(int), stream);

  btbuild<<<128, 384, 0, stream>>>(W1, root1, Bt1);
  btbuild<<<128, 384, 0, stream>>>(W2, root2, Bt2);
  xstage<<<(N * 64 + 255) / 256, 256, 0, stream>>>(x, aggbuf1, N);

  bucket_hist<<<nchunk, 256, 0, stream>>>(ea, eb, E, NB, bucket_cnt);
  bucket_scan<<<1, 256, 0, stream>>>(bucket_cnt, bucket_base, bucket_cursor, NB);
  bucket_bin<<<nchunk, 256, 0, stream>>>(ea, eb, E, NB, bucket_cursor, staging);
  bucket_build<<<NB, 256, 0, stream>>>(staging, bucket_base, bucket_cnt,
                                       csr, offs, ends, nseg);

  const int agg_blocks = (nseg + 3) / 4;  // 4 waves/block, 1 wave/segment

  // layer 1
  agg_kernel<<<agg_blocks, 256, 0, stream>>>(aggbuf1, csr, offs, ends, aggbuf1, nseg);
  mfma_gemm<1><<<Mblk, 256, 0, stream>>>(aggbuf1, Bt1, b1, nullptr, aggbuf2, N);

  // layer 2
  agg_kernel<<<agg_blocks, 256, 0, stream>>>(aggbuf2, csr, offs, ends, aggbuf2, nseg);
  mfma_gemm<0><<<Mblk, 256, 0, stream>>>(aggbuf2, Bt2, b2, out, nullptr, N);
}

// Round 5
// 340.169 us; speedup vs baseline: 2.7482x; 1.1202x over previous
//
#include <hip/hip_runtime.h>
#include <hip/hip_bf16.h>

// RGCN (2 relations, d=128, two layers) for MI355X — round 5.
// Aggregate-then-transform, bf16 MFMA GEMM (16x16x32).
//   A[n] = [mean_r0 | mean_r1 | x_n]  (384 bf16, contiguous)
//   out[n] = A[n] @ [W0; W1; root] + bias   (one fused GEMM per layer)
// Round-5 change: GEMM rewritten — B staged in LDS (two K=192 chunks,
// padded row stride 400 B -> ~2-way-free ds_read_b128), 4 waves x 64 rows
// per wave (32 MFMAs per k-step), fully-unrolled inner loop with explicit
// A-fragment ping-pong for memory-level parallelism.

typedef __attribute__((ext_vector_type(8))) short bf16x8;
typedef __attribute__((ext_vector_type(4))) float f32x4;
typedef unsigned short ushort_t;
typedef unsigned int uint_t;

#define BSHIFT 9                      // bucket = dst >> 9 (512 nodes/bucket)
#define SEGB (1 << (BSHIFT + 1))      // 1024 segments per bucket
#define NBMAX 256
#define CH_PER_THREAD 16
#define CHUNK (256 * CH_PER_THREAD)   // 4096 edges per bin block

#define GBM 256                       // GEMM rows per block
#define KCH 192                       // GEMM k per LDS chunk
#define LDBB 400                      // LDS B row stride in BYTES (200 elems)

__device__ __forceinline__ float b2fu(uint_t u) {  // low 16 bits -> float
  union { uint_t u; float f; } v;
  v.u = u << 16;
  return v.f;
}
__device__ __forceinline__ ushort_t f2b(float f) {
  union { float f; uint_t u; } v;
  v.f = f;
  uint_t u = v.u;
  return (ushort_t)((u + 0x7FFFu + ((u >> 16) & 1u)) >> 16);  // RNE
}

// ---------------- B build: Bt[c][k] = bf16( k<256 ? W[k][c] : root[k-256][c] )
__global__ __launch_bounds__(384) void btbuild(
    const float* __restrict__ W, const float* __restrict__ root,
    ushort_t* __restrict__ Bt) {
  int c = blockIdx.x;
  int k = threadIdx.x;
  float v = (k < 256) ? W[(size_t)k * 128 + c] : root[(size_t)(k - 256) * 128 + c];
  Bt[(size_t)c * 384 + k] = f2b(v);
}

// ---------------- stage x (fp32) -> aggbuf1[n][256..384) bf16
__global__ __launch_bounds__(256) void xstage(
    const float* __restrict__ x, ushort_t* __restrict__ aggbuf, int N) {
  int idx = blockIdx.x * blockDim.x + threadIdx.x;
  int n = idx >> 6, lane = idx & 63;
  if (n >= N) return;
  float2 v = *(const float2*)(x + (size_t)n * 128 + lane * 2);
  uint_t pk = (uint_t)f2b(v.x) | ((uint_t)f2b(v.y) << 16);
  *(uint_t*)(aggbuf + (size_t)n * 384 + 256 + lane * 2) = pk;
}

// ---------------- CSR build: bucketed counting sort ----------------
__global__ __launch_bounds__(256) void bucket_hist(
    const int* __restrict__ ea, const int* __restrict__ eb,
    int E, int NB, int* __restrict__ bucket_cnt) {
  __shared__ int h[NBMAX];
  for (int i = threadIdx.x; i < NB; i += 256) h[i] = 0;
  __syncthreads();
  int tbase = blockIdx.x * CHUNK + threadIdx.x;
  int total = 2 * E;
#pragma unroll
  for (int j = 0; j < CH_PER_THREAD; ++j) {
    int i = tbase + j * 256;
    if (i < total) {
      int dst = (i < E) ? ea[E + i] : eb[i];
      atomicAdd(&h[dst >> BSHIFT], 1);
    }
  }
  __syncthreads();
  for (int i = threadIdx.x; i < NB; i += 256)
    if (h[i]) atomicAdd(&bucket_cnt[i], h[i]);
}

__global__ __launch_bounds__(256) void bucket_scan(
    const int* __restrict__ bucket_cnt, int* __restrict__ bucket_base,
    int* __restrict__ bucket_cursor, int NB) {
  __shared__ int sdata[256];
  int v = (threadIdx.x < NB) ? bucket_cnt[threadIdx.x] : 0;
  sdata[threadIdx.x] = v;
  __syncthreads();
  for (int off = 1; off < 256; off <<= 1) {
    int t = (threadIdx.x >= (unsigned)off) ? sdata[threadIdx.x - off] : 0;
    __syncthreads();
    sdata[threadIdx.x] += t;
    __syncthreads();
  }
  if (threadIdx.x < NB) {
    int e = sdata[threadIdx.x] - v;
    bucket_base[threadIdx.x] = e;
    bucket_cursor[threadIdx.x] = e;
  }
}

__global__ __launch_bounds__(256) void bucket_bin(
    const int* __restrict__ ea, const int* __restrict__ eb,
    int E, int NB, int* __restrict__ bucket_cursor,
    uint2* __restrict__ staging) {
  __shared__ int h[NBMAX];
  __shared__ int bbase[NBMAX];
  for (int i = threadIdx.x; i < NB; i += 256) h[i] = 0;
  __syncthreads();
  int tbase = blockIdx.x * CHUNK + threadIdx.x;
  int total = 2 * E;
  uint2 val[CH_PER_THREAD];
#pragma unroll
  for (int j = 0; j < CH_PER_THREAD; ++j) {
    int i = tbase + j * 256;
    if (i < total) {
      int src, dst, rel;
      if (i < E) { src = ea[i];     dst = ea[E + i]; rel = 0; }
      else       { src = eb[i - E]; dst = eb[i];     rel = 1; }
      val[j].x = (uint_t)src;
      val[j].y = (uint_t)(dst * 2 + rel);
      atomicAdd(&h[dst >> BSHIFT], 1);
    } else {
      val[j].y = 0xffffffffu;
    }
  }
  __syncthreads();
  for (int i = threadIdx.x; i < NB; i += 256) {
    int c = h[i];
    bbase[i] = c ? atomicAdd(&bucket_cursor[i], c) : 0;
    h[i] = 0;
  }
  __syncthreads();
#pragma unroll
  for (int j = 0; j < CH_PER_THREAD; ++j) {
    if (val[j].y != 0xffffffffu) {
      int bkt = (int)(val[j].y >> (BSHIFT + 1));
      int r = atomicAdd(&h[bkt], 1);
      staging[(size_t)bbase[bkt] + r] = val[j];
    }
  }
}

__global__ __launch_bounds__(256) void bucket_build(
    const uint2* __restrict__ staging,
    const int* __restrict__ bucket_base, const int* __restrict__ bucket_cnt,
    int* __restrict__ csr, int* __restrict__ offs, int* __restrict__ ends,
    int nseg) {
  __shared__ int scnt[SEGB];
  __shared__ int sexcl[SEGB];
  __shared__ int sdata[256];
  int b = blockIdx.x;
  int base = bucket_base[b];
  int ne = bucket_cnt[b];
  int seg0 = b << (BSHIFT + 1);
  int t = threadIdx.x;
  for (int i = t; i < SEGB; i += 256) scnt[i] = 0;
  __syncthreads();
  const uint2* st = staging + base;
  for (int i = t; i < ne; i += 256) {
    int seg = (int)st[i].y - seg0;
    atomicAdd(&scnt[seg], 1);
  }
  __syncthreads();
  int c0 = scnt[t * 4 + 0], c1 = scnt[t * 4 + 1];
  int c2 = scnt[t * 4 + 2], c3 = scnt[t * 4 + 3];
  int s = c0 + c1 + c2 + c3;
  sdata[t] = s;
  __syncthreads();
  for (int off = 1; off < 256; off <<= 1) {
    int tmp = (t >= (unsigned)off) ? sdata[t - off] : 0;
    __syncthreads();
    sdata[t] += tmp;
    __syncthreads();
  }
  int excl = sdata[t] - s;
  int e0 = excl, e1 = excl + c0, e2 = e1 + c1, e3 = e2 + c2;
  sexcl[t * 4 + 0] = e0;
  sexcl[t * 4 + 1] = e1;
  sexcl[t * 4 + 2] = e2;
  sexcl[t * 4 + 3] = e3;
  {
    int g = seg0 + t * 4;
    if (g + 0 < nseg) { offs[g + 0] = base + e0; ends[g + 0] = base + e0 + c0; }
    if (g + 1 < nseg) { offs[g + 1] = base + e1; ends[g + 1] = base + e1 + c1; }
    if (g + 2 < nseg) { offs[g + 2] = base + e2; ends[g + 2] = base + e2 + c2; }
    if (g + 3 < nseg) { offs[g + 3] = base + e3; ends[g + 3] = base + e3 + c3; }
  }
  scnt[t * 4 + 0] = 0;
  scnt[t * 4 + 1] = 0;
  scnt[t * 4 + 2] = 0;
  scnt[t * 4 + 3] = 0;
  __syncthreads();
  for (int i = t; i < ne; i += 256) {
    uint2 v = st[i];
    int seg = (int)v.y - seg0;
    int r = atomicAdd(&scnt[seg], 1);
    csr[base + sexcl[seg] + r] = (int)v.x;
  }
}

// ---------------- aggregation: one wave per segment, quarter-wave per edge --
__device__ __forceinline__ void accum8(float* acc, uint4 v) {
  acc[0] += b2fu(v.x); acc[1] += b2fu(v.x >> 16);
  acc[2] += b2fu(v.y); acc[3] += b2fu(v.y >> 16);
  acc[4] += b2fu(v.z); acc[5] += b2fu(v.z >> 16);
  acc[6] += b2fu(v.w); acc[7] += b2fu(v.w >> 16);
}

__global__ __launch_bounds__(256) void agg_kernel(
    const ushort_t* __restrict__ xb,   // rows at xb[n*384 + 256 ..]
    const int* __restrict__ csr,
    const int* __restrict__ offs, const int* __restrict__ ends,
    ushort_t* __restrict__ agg, int nseg) {
  int wid = (blockIdx.x * blockDim.x + threadIdx.x) >> 6;
  if (wid >= nseg) return;
  int lane = threadIdx.x & 63;
  int q = lane >> 4;
  int t = lane & 15;
  int beg = offs[wid], end = ends[wid];

  float acc[8];
#pragma unroll
  for (int j = 0; j < 8; ++j) acc[j] = 0.f;

  int e = beg + q;
  for (; e + 4 < end; e += 8) {
    int s0 = csr[e];
    int s1 = csr[e + 4];
    uint4 v0 = *(const uint4*)(xb + (size_t)s0 * 384 + 256 + t * 8);
    uint4 v1 = *(const uint4*)(xb + (size_t)s1 * 384 + 256 + t * 8);
    accum8(acc, v0);
    accum8(acc, v1);
  }
  if (e < end) {
    int s0 = csr[e];
    uint4 v0 = *(const uint4*)(xb + (size_t)s0 * 384 + 256 + t * 8);
    accum8(acc, v0);
  }

#pragma unroll
  for (int j = 0; j < 8; ++j) {
    acc[j] += __shfl_xor(acc[j], 16);
    acc[j] += __shfl_xor(acc[j], 32);
  }

  int c = end - beg;
  float inv = 1.0f / (float)(c > 1 ? c : 1);
  if (q == 0) {
    uint4 o;
    o.x = (uint_t)f2b(acc[0] * inv) | ((uint_t)f2b(acc[1] * inv) << 16);
    o.y = (uint_t)f2b(acc[2] * inv) | ((uint_t)f2b(acc[3] * inv) << 16);
    o.z = (uint_t)f2b(acc[4] * inv) | ((uint_t)f2b(acc[5] * inv) << 16);
    o.w = (uint_t)f2b(acc[6] * inv) | ((uint_t)f2b(acc[7] * inv) << 16);
    int n = wid >> 1, r = wid & 1;
    *(uint4*)(agg + (size_t)n * 384 + r * 128 + t * 8) = o;
  }
}

// ---------------- MFMA GEMM: [M x 384] bf16 @ [384 x 128] bf16 -> f32 ------
// Block = 4 waves x 256 threads, 256 rows (wave w: rows w*64..w*64+63).
// B staged in LDS in two K=192 chunks, row stride 400 B (2-way-free reads).
// Per k-step/wave: 4 A global loads + 8 ds_read_b128 -> 32 MFMAs.

__device__ __forceinline__ void do_mfma32(
    const ushort_t* Bs, f32x4 (&acc)[4][8], const bf16x8 (&a)[4],
    int ks, int lrow, int kg) {
  bf16x8 b[8];
#pragma unroll
  for (int c = 0; c < 8; ++c)
    b[c] = *(const bf16x8*)((const char*)Bs + (c * 16 + lrow) * LDBB +
                            (ks * 4 + kg) * 16);
#pragma unroll
  for (int r = 0; r < 4; ++r)
#pragma unroll
    for (int c = 0; c < 8; ++c)
      acc[r][c] = __builtin_amdgcn_mfma_f32_16x16x32_bf16(a[r], b[c], acc[r][c], 0, 0, 0);
}

template <int MODE>
__global__ __launch_bounds__(256, 2) void mfma_gemm(
    const ushort_t* __restrict__ A,   // [Mpad][384]
    const ushort_t* __restrict__ Bt,  // [128][384]
    const float* __restrict__ bias,   // [128]
    float* __restrict__ outf,
    ushort_t* __restrict__ outb,
    int M) {
  __shared__ __align__(16) ushort_t Bs[128 * (LDBB / 2)];  // 51200 B
  const int tid = threadIdx.x;
  const int lane = tid & 63;
  const int wave = tid >> 6;
  const int lrow = lane & 15;
  const int kg = lane >> 4;
  const int rowbase = blockIdx.x * GBM + wave * 64;

  f32x4 acc[4][8];
#pragma unroll
  for (int r = 0; r < 4; ++r)
#pragma unroll
    for (int c = 0; c < 8; ++c) acc[r][c] = (f32x4){0.f, 0.f, 0.f, 0.f};

  for (int ch = 0; ch < 2; ++ch) {
    // ---- stage B chunk ch into LDS: 3072 uint4, 12 per thread
#pragma unroll
    for (int j = 0; j < 12; ++j) {
      int flat = tid + j * 256;       // 0..3071
      int col = flat / 24;            // 24 x 16B quads per col-chunk
      int q = flat - col * 24;
      uint4 v = *(const uint4*)(Bt + (size_t)col * 384 + ch * KCH + q * 8);
      *(uint4*)((char*)Bs + col * LDBB + q * 16) = v;
    }
    __syncthreads();

    // ---- compute 6 k-steps with A ping-pong
    const ushort_t* ab = A + (size_t)ch * KCH + kg * 8;
    bf16x8 aA[4], aB[4];
#pragma unroll
    for (int r = 0; r < 4; ++r)
      aA[r] = *(const bf16x8*)(ab + (size_t)(rowbase + r * 16 + lrow) * 384);
#pragma unroll
    for (int ks2 = 0; ks2 < 3; ++ks2) {
      {  // even step: compute aA, prefetch aB
        const int ks = ks2 * 2;
#pragma unroll
        for (int r = 0; r < 4; ++r)
          aB[r] = *(const bf16x8*)(ab + (size_t)(rowbase + r * 16 + lrow) * 384 +
                                   (ks + 1) * 32);
        do_mfma32(Bs, acc, aA, ks, lrow, kg);
      }
      {  // odd step: compute aB, prefetch aA
        const int ks = ks2 * 2 + 1;
        if (ks < 5) {
#pragma unroll
          for (int r = 0; r < 4; ++r)
            aA[r] = *(const bf16x8*)(ab + (size_t)(rowbase + r * 16 + lrow) * 384 +
                                     (ks + 1) * 32);
        }
        do_mfma32(Bs, acc, aB, ks, lrow, kg);
      }
    }
    __syncthreads();
  }

  // ---- epilogue
#pragma unroll
  for (int c = 0; c < 8; ++c) {
    int col = c * 16 + lrow;
    float bv = bias[col];
#pragma unroll
    for (int r = 0; r < 4; ++r) {
      int r0 = rowbase + r * 16 + kg * 4;
#pragma unroll
      for (int j = 0; j < 4; ++j) {
        int row = r0 + j;
        if (row < M) {
          float v = acc[r][c][j] + bv;
          if (MODE == 1) {
            v = fmaxf(v, 0.f);
            outb[(size_t)row * 384 + 256 + col] = f2b(v);
          } else {
            outf[(size_t)row * 128 + col] = v;
          }
        }
      }
    }
  }
}

// ---------------- launch ----------------
extern "C" void kernel_launch(void* const* d_in, const int* in_sizes, int n_in,
                              void* d_out, int out_size, void* d_ws, size_t ws_size,
                              hipStream_t stream) {
  const float* x     = (const float*)d_in[0];
  const int*   ea    = (const int*)d_in[1];
  const int*   eb    = (const int*)d_in[2];
  const float* W1    = (const float*)d_in[3];
  const float* root1 = (const float*)d_in[4];
  const float* b1    = (const float*)d_in[5];
  const float* W2    = (const float*)d_in[6];
  const float* root2 = (const float*)d_in[7];
  const float* b2    = (const float*)d_in[8];
  float* out = (float*)d_out;

  const int N = in_sizes[0] / 128;
  const int E = in_sizes[1] / 2;
  const int nseg = N * 2;
  const int Mblk = (N + GBM - 1) / GBM;           // 391
  const int Mpad = Mblk * GBM;                    // 100096
  const int NB = ((N - 1) >> BSHIFT) + 1;         // 196
  const int nchunk = (2 * E + CHUNK - 1) / CHUNK; // 391

  // workspace carve-up (all 16B-aligned)
  char* p = (char*)d_ws;
  ushort_t* aggbuf1 = (ushort_t*)p;  p += (size_t)Mpad * 384 * sizeof(ushort_t);
  ushort_t* aggbuf2 = (ushort_t*)p;  p += (size_t)Mpad * 384 * sizeof(ushort_t);
  ushort_t* Bt1 = (ushort_t*)p;      p += (size_t)128 * 384 * sizeof(ushort_t);
  ushort_t* Bt2 = (ushort_t*)p;      p += (size_t)128 * 384 * sizeof(ushort_t);
  int* csr = (int*)p;                p += (size_t)2 * E * sizeof(int);
  int* offs = (int*)p;               p += (size_t)nseg * sizeof(int);
  int* ends = (int*)p;               p += (size_t)nseg * sizeof(int);
  int* bucket_cnt = (int*)p;         p += NBMAX * sizeof(int);
  int* bucket_base = (int*)p;        p += NBMAX * sizeof(int);
  int* bucket_cursor = (int*)p;      p += NBMAX * sizeof(int);
  // staging (2E uint2 = 12.8 MB) aliases aggbuf2 (dead until gemm1 writes it)
  uint2* staging = (uint2*)aggbuf2;

  hipMemsetAsync(bucket_cnt, 0, NBMAX * sizeof(int), stream);

  btbuild<<<128, 384, 0, stream>>>(W1, root1, Bt1);
  btbuild<<<128, 384, 0, stream>>>(W2, root2, Bt2);
  xstage<<<(N * 64 + 255) / 256, 256, 0, stream>>>(x, aggbuf1, N);

  bucket_hist<<<nchunk, 256, 0, stream>>>(ea, eb, E, NB, bucket_cnt);
  bucket_scan<<<1, 256, 0, stream>>>(bucket_cnt, bucket_base, bucket_cursor, NB);
  bucket_bin<<<nchunk, 256, 0, stream>>>(ea, eb, E, NB, bucket_cursor, staging);
  bucket_build<<<NB, 256, 0, stream>>>(staging, bucket_base, bucket_cnt,
                                       csr, offs, ends, nseg);

  const int agg_blocks = (nseg + 3) / 4;  // 4 waves/block, 1 wave/segment

  // layer 1
  agg_kernel<<<agg_blocks, 256, 0, stream>>>(aggbuf1, csr, offs, ends, aggbuf1, nseg);
  mfma_gemm<1><<<Mblk, 256, 0, stream>>>(aggbuf1, Bt1, b1, nullptr, aggbuf2, N);

  // layer 2
  agg_kernel<<<agg_blocks, 256, 0, stream>>>(aggbuf2, csr, offs, ends, aggbuf2, nseg);
  mfma_gemm<0><<<Mblk, 256, 0, stream>>>(aggbuf2, Bt2, b2, out, nullptr, N);
}